// Round 1
// baseline (5798.452 us; speedup 1.0000x reference)
//
#include <hip/hip_runtime.h>
#include <cstddef>
#include <cstdint>

namespace {

constexpr int kB  = 4096;   // batch
constexpr int kIN = 4096;
constexpr int kFS = 4096;
constexpr int kS  = 64;
constexpr int kH  = 512;
constexpr int kNG = 2048;   // 4*H
constexpr int kKC = 576;    // 64 (input slice) + 512 (hidden)
constexpr int kKTiles = kKC / 32;  // 18

typedef __bf16 bf16_t;
typedef __bf16 bfrag  __attribute__((ext_vector_type(8)));
typedef __bf16 bf16v4 __attribute__((ext_vector_type(4)));
typedef float  f32x4  __attribute__((ext_vector_type(4)));

__device__ __forceinline__ void gload16(const void* g, void* l) {
  __builtin_amdgcn_global_load_lds(
      (const __attribute__((address_space(1))) void*)g,
      (__attribute__((address_space(3))) void*)l, 16, 0, 0);
}

__device__ __forceinline__ float sigf(float x) { return 1.0f / (1.0f + __expf(-x)); }

// ---------------- pack kernels ----------------

__global__ __launch_bounds__(256) void f2b4_kernel(const float* __restrict__ in,
                                                   bf16_t* __restrict__ out, int n4) {
  int i = blockIdx.x * 256 + threadIdx.x;
  if (i >= n4) return;
  float4 v = reinterpret_cast<const float4*>(in)[i];
  bf16v4 o = {(bf16_t)v.x, (bf16_t)v.y, (bf16_t)v.z, (bf16_t)v.w};
  *reinterpret_cast<bf16v4*>(out + (size_t)i * 4) = o;
}

// Wcat[m] (2048 x 576) bf16, rows gate-interleaved: new row u*4+gate <- old row gate*512+u.
// k<64: Wih, k>=64: Whh. m: 0=left, 1=right, 2=up/down (shared).
__global__ __launch_bounds__(256) void pack_wcat_kernel(
    const float* __restrict__ Wih_l, const float* __restrict__ Whh_l,
    const float* __restrict__ Wih_r, const float* __restrict__ Whh_r,
    const float* __restrict__ Wih_d, const float* __restrict__ Whh_d,
    bf16_t* __restrict__ wcat) {
  int idx = blockIdx.x * 256 + threadIdx.x;
  if (idx >= 3 * kNG * kKC) return;
  int m = idx / (kNG * kKC);
  int rem = idx - m * (kNG * kKC);
  int rr = rem / kKC;
  int k  = rem - rr * kKC;
  int u = rr >> 2, g = rr & 3;
  int orow = g * kH + u;
  const float* Wih = (m == 0) ? Wih_l : (m == 1) ? Wih_r : Wih_d;
  const float* Whh = (m == 0) ? Whh_l : (m == 1) ? Whh_r : Whh_d;
  float v = (k < 64) ? Wih[(size_t)orow * 64 + k] : Whh[(size_t)orow * 512 + (k - 64)];
  wcat[idx] = (bf16_t)v;
}

__global__ __launch_bounds__(256) void pack_bias_kernel(
    const float* __restrict__ bih_l, const float* __restrict__ bhh_l,
    const float* __restrict__ bih_r, const float* __restrict__ bhh_r,
    const float* __restrict__ bih_d, const float* __restrict__ bhh_d,
    float* __restrict__ biasc) {
  int idx = blockIdx.x * 256 + threadIdx.x;
  if (idx >= 3 * kNG) return;
  int m = idx / kNG;
  int rr = idx - m * kNG;
  int u = rr >> 2, g = rr & 3;
  int orow = g * kH + u;
  const float* bi = (m == 0) ? bih_l : (m == 1) ? bih_r : bih_d;
  const float* bh = (m == 0) ? bhh_l : (m == 1) ? bhh_r : bhh_d;
  biasc[idx] = bi[orow] + bh[orow];
}

__global__ __launch_bounds__(256) void pack_hc_kernel(const float* __restrict__ h0,
                                                      const float* __restrict__ c0,
                                                      bf16_t* __restrict__ hbuf0,
                                                      float* __restrict__ cbuf, int n) {
  int i = blockIdx.x * 256 + threadIdx.x;
  if (i >= n) return;
  hbuf0[i] = (bf16_t)h0[i];
  cbuf[i]  = c0[i];
}

// per-batch-row 64x64 transpose: featT[b][t*64+s] = feat[b][s*64+t]
__global__ __launch_bounds__(256) void transpose64_kernel(const bf16_t* __restrict__ feat,
                                                          bf16_t* __restrict__ featT) {
  __shared__ bf16_t tile[64][65];
  const int b = blockIdx.x;
  const bf16_t* src = feat + (size_t)b * kFS;
  bf16_t* dst = featT + (size_t)b * kFS;
  for (int i = threadIdx.x; i < 4096; i += 256) tile[i >> 6][i & 63] = src[i];
  __syncthreads();
  for (int i = threadIdx.x; i < 4096; i += 256) dst[i] = tile[i & 63][i >> 6];
}

// ---------------- feat GEMM: feat = relu(x @ W1^T + b1), bf16 in/out, fp32 acc ----------------

__global__ __launch_bounds__(256) void gemm_feat_kernel(
    const bf16_t* __restrict__ X, const bf16_t* __restrict__ W,
    const float* __restrict__ b1, bf16_t* __restrict__ feat) {
  __shared__ bf16_t As[128 * 32];
  __shared__ bf16_t Bs[128 * 32];
  const int t = threadIdx.x;
  const int bm = blockIdx.x, bn = blockIdx.y;
  const int w = t >> 6, l = t & 63;
  const int wm = (w >> 1) * 64, wn = (w & 1) * 64;
  const int sr = t >> 2, sk = (t & 3) * 8;
  const int lr = l & 15, lk = (l >> 4) * 8;
  const int lrow4 = (l >> 4) * 4;

  f32x4 acc[4][4];
#pragma unroll
  for (int i = 0; i < 4; ++i)
#pragma unroll
    for (int j = 0; j < 4; ++j) acc[i][j] = (f32x4){0.f, 0.f, 0.f, 0.f};

  const bf16_t* ga = X + (size_t)(bm * 128 + sr) * kIN + sk;
  const bf16_t* gb = W + (size_t)(bn * 128 + sr) * kIN + sk;
  bf16_t* lA = As + w * 512;
  bf16_t* lB = Bs + w * 512;

  for (int kt = 0; kt < kIN / 32; ++kt) {
    gload16(ga, lA);
    gload16(ga + (size_t)64 * kIN, lA + 2048);
    gload16(gb, lB);
    gload16(gb + (size_t)64 * kIN, lB + 2048);
    ga += 32; gb += 32;
    __syncthreads();
    bfrag a[4], b[4];
#pragma unroll
    for (int mi = 0; mi < 4; ++mi)
      a[mi] = *reinterpret_cast<const bfrag*>(&As[(wm + mi * 16 + lr) * 32 + lk]);
#pragma unroll
    for (int ni = 0; ni < 4; ++ni)
      b[ni] = *reinterpret_cast<const bfrag*>(&Bs[(wn + ni * 16 + lr) * 32 + lk]);
#pragma unroll
    for (int mi = 0; mi < 4; ++mi)
#pragma unroll
      for (int ni = 0; ni < 4; ++ni)
        acc[mi][ni] = __builtin_amdgcn_mfma_f32_16x16x32_bf16(a[mi], b[ni], acc[mi][ni], 0, 0, 0);
    __syncthreads();
  }

#pragma unroll
  for (int ni = 0; ni < 4; ++ni) {
    const int col = bn * 128 + wn + ni * 16 + lr;
    const float bb = b1[col];
#pragma unroll
    for (int mi = 0; mi < 4; ++mi) {
#pragma unroll
      for (int r = 0; r < 4; ++r) {
        const int row = bm * 128 + wm + mi * 16 + lrow4 + r;
        float v = acc[mi][ni][r] + bb;
        feat[(size_t)row * kFS + col] = (bf16_t)fmaxf(v, 0.0f);
      }
    }
  }
}

// ---------------- fused LSTM step: g = [x_s | h] @ Wcat^T + b -> gates -> c,h ----------------

__global__ __launch_bounds__(256) void lstm_step_kernel(
    const bf16_t* __restrict__ feat, const bf16_t* __restrict__ featT,
    const bf16_t* __restrict__ wcat, const float* __restrict__ biasc,
    const bf16_t* __restrict__ hin, bf16_t* __restrict__ hout,
    float* __restrict__ cbuf, int s) {
  __shared__ bf16_t As[128 * 32];
  __shared__ bf16_t Bs[128 * 32];
  __shared__ float Gs[64 * 128];
  const int t = threadIdx.x;
  const int bm = blockIdx.x, bn = blockIdx.y, cell = blockIdx.z;
  const int w = t >> 6, l = t & 63;
  const int wm = (w >> 1) * 64, wn = (w & 1) * 64;
  const int sr = t >> 2, sk = (t & 3) * 8;
  const int lr = l & 15, lk = (l >> 4) * 8;
  const int lrow4 = (l >> 4) * 4;

  const bf16_t* xsrc = (cell < 2) ? feat : featT;
  const int off = ((cell & 1) ? (63 - s) : s) * 64;
  const int mat = (cell < 2) ? cell : 2;
  const bf16_t* Wm = wcat + (size_t)mat * kNG * kKC;
  const float* bias = biasc + mat * kNG;
  const bf16_t* hc = hin + (size_t)cell * kB * kH;

  f32x4 acc[4][4];
#pragma unroll
  for (int i = 0; i < 4; ++i)
#pragma unroll
    for (int j = 0; j < 4; ++j) acc[i][j] = (f32x4){0.f, 0.f, 0.f, 0.f};

  const bf16_t* gax = xsrc + (size_t)(bm * 128 + sr) * kFS + off + sk;
  const bf16_t* gah = hc + (size_t)(bm * 128 + sr) * kH + sk;
  const bf16_t* gb  = Wm + (size_t)(bn * 128 + sr) * kKC + sk;
  bf16_t* lA = As + w * 512;
  bf16_t* lB = Bs + w * 512;

  for (int kt = 0; kt < kKTiles; ++kt) {
    if (kt < 2) {  // input-slice part of K (contiguous 64 cols of feat/featT)
      const bf16_t* ga = gax + kt * 32;
      gload16(ga, lA);
      gload16(ga + (size_t)64 * kFS, lA + 2048);
    } else {       // hidden part of K
      const bf16_t* ga = gah + (kt - 2) * 32;
      gload16(ga, lA);
      gload16(ga + (size_t)64 * kH, lA + 2048);
    }
    gload16(gb, lB);
    gload16(gb + (size_t)64 * kKC, lB + 2048);
    gb += 32;
    __syncthreads();
    bfrag a[4], b[4];
#pragma unroll
    for (int mi = 0; mi < 4; ++mi)
      a[mi] = *reinterpret_cast<const bfrag*>(&As[(wm + mi * 16 + lr) * 32 + lk]);
#pragma unroll
    for (int ni = 0; ni < 4; ++ni)
      b[ni] = *reinterpret_cast<const bfrag*>(&Bs[(wn + ni * 16 + lr) * 32 + lk]);
#pragma unroll
    for (int mi = 0; mi < 4; ++mi)
#pragma unroll
      for (int ni = 0; ni < 4; ++ni)
        acc[mi][ni] = __builtin_amdgcn_mfma_f32_16x16x32_bf16(a[mi], b[ni], acc[mi][ni], 0, 0, 0);
    __syncthreads();
  }

  // Epilogue: repack g into LDS (gate-interleaved cols -> complete units), fuse gates.
  const float* biasn = bias + bn * 128;
#pragma unroll
  for (int half = 0; half < 2; ++half) {
    if ((w >> 1) == half) {
#pragma unroll
      for (int ni = 0; ni < 4; ++ni) {
        const int colL = wn + ni * 16 + lr;
        const float bb = biasn[colL];
#pragma unroll
        for (int mi = 0; mi < 4; ++mi)
#pragma unroll
          for (int r = 0; r < 4; ++r)
            Gs[(mi * 16 + lrow4 + r) * 128 + colL] = acc[mi][ni][r] + bb;
      }
    }
    __syncthreads();
#pragma unroll
    for (int it = 0; it < 8; ++it) {
      const int ci = it * 256 + t;          // 64 rows x 32 units
      const int rowL = ci >> 5;
      const int u = ci & 31;
      const float4 g4 = *reinterpret_cast<const float4*>(&Gs[rowL * 128 + u * 4]);
      const float iv = sigf(g4.x);
      const float fv = sigf(g4.y);
      const float gv = tanhf(g4.z);
      const float ov = sigf(g4.w);
      const int batch = bm * 128 + half * 64 + rowL;
      const int unit = bn * 32 + u;
      const size_t cidx = ((size_t)cell * kB + batch) * kH + unit;
      const float cn = fv * cbuf[cidx] + iv * gv;
      cbuf[cidx] = cn;
      hout[cidx] = (bf16_t)(ov * tanhf(cn));
    }
    __syncthreads();
  }
}

// ---------------- head: logits = [hl|hr|hu|hd] @ W3^T + b3 ; log_softmax ----------------

__global__ __launch_bounds__(256) void head_kernel(const bf16_t* __restrict__ hfin,
                                                   const float* __restrict__ W3,
                                                   const float* __restrict__ b3,
                                                   float* __restrict__ out) {
  const int b = blockIdx.x, t = threadIdx.x;
  float acc[10];
#pragma unroll
  for (int j = 0; j < 10; ++j) acc[j] = 0.f;
  for (int k = t; k < 2048; k += 256) {
    const int cell = k >> 9, u = k & 511;
    const float hv = (float)hfin[((size_t)cell * kB + b) * kH + u];
#pragma unroll
    for (int j = 0; j < 10; ++j) acc[j] += hv * W3[j * 2048 + k];
  }
  __shared__ float red[256];
  __shared__ float logits[10];
  for (int j = 0; j < 10; ++j) {
    red[t] = acc[j];
    __syncthreads();
    for (int o2 = 128; o2 > 0; o2 >>= 1) {
      if (t < o2) red[t] += red[t + o2];
      __syncthreads();
    }
    if (t == 0) logits[j] = red[0] + b3[j];
    __syncthreads();
  }
  if (t == 0) {
    float mx = logits[0];
    for (int j = 1; j < 10; ++j) mx = fmaxf(mx, logits[j]);
    float se = 0.f;
    for (int j = 0; j < 10; ++j) se += expf(logits[j] - mx);
    const float lse = mx + logf(se);
    for (int j = 0; j < 10; ++j) out[(size_t)b * 10 + j] = logits[j] - lse;
  }
}

}  // namespace

extern "C" void kernel_launch(void* const* d_in, const int* in_sizes, int n_in,
                              void* d_out, int out_size, void* d_ws, size_t ws_size,
                              hipStream_t stream) {
  const float* x     = (const float*)d_in[0];
  const float* h0    = (const float*)d_in[1];
  const float* c0    = (const float*)d_in[2];
  const float* W1    = (const float*)d_in[3];
  const float* b1    = (const float*)d_in[4];
  const float* Wih_l = (const float*)d_in[5];
  const float* Whh_l = (const float*)d_in[6];
  const float* bih_l = (const float*)d_in[7];
  const float* bhh_l = (const float*)d_in[8];
  const float* Wih_r = (const float*)d_in[9];
  const float* Whh_r = (const float*)d_in[10];
  const float* bih_r = (const float*)d_in[11];
  const float* bhh_r = (const float*)d_in[12];
  const float* Wih_d = (const float*)d_in[13];
  const float* Whh_d = (const float*)d_in[14];
  const float* bih_d = (const float*)d_in[15];
  const float* bhh_d = (const float*)d_in[16];
  const float* W3    = (const float*)d_in[17];
  const float* b3    = (const float*)d_in[18];
  float* out = (float*)d_out;

  char* p = (char*)d_ws;
  auto take = [&](size_t bytes) {
    char* r = p;
    p += (bytes + 255) & ~(size_t)255;
    return r;
  };
  bf16_t* xb    = (bf16_t*)take((size_t)kB * kIN * 2);   // later reused as featT
  bf16_t* w1b   = (bf16_t*)take((size_t)kFS * kIN * 2);  // later reused as hbuf (2 slots)
  bf16_t* feat  = (bf16_t*)take((size_t)kB * kFS * 2);
  bf16_t* wcat  = (bf16_t*)take((size_t)3 * kNG * kKC * 2);
  float*  biasc = (float*)take((size_t)3 * kNG * 4);
  float*  cbuf  = (float*)take((size_t)4 * kB * kH * 4);
  bf16_t* featT = xb;   // safe: gemm_feat (reads xb) precedes transpose (writes featT)
  bf16_t* hbuf  = w1b;  // safe: gemm_feat (reads w1b) precedes pack_hc; 2*4*B*H*2 == FS*IN*2
  const size_t HSZ = (size_t)4 * kB * kH;

  f2b4_kernel<<<(kB * kIN / 4) / 256, 256, 0, stream>>>(x, xb, kB * kIN / 4);
  f2b4_kernel<<<(kFS * kIN / 4) / 256, 256, 0, stream>>>(W1, w1b, kFS * kIN / 4);
  gemm_feat_kernel<<<dim3(32, 32), 256, 0, stream>>>(xb, w1b, b1, feat);
  transpose64_kernel<<<kB, 256, 0, stream>>>(feat, featT);
  pack_wcat_kernel<<<(3 * kNG * kKC + 255) / 256, 256, 0, stream>>>(
      Wih_l, Whh_l, Wih_r, Whh_r, Wih_d, Whh_d, wcat);
  pack_bias_kernel<<<(3 * kNG + 255) / 256, 256, 0, stream>>>(
      bih_l, bhh_l, bih_r, bhh_r, bih_d, bhh_d, biasc);
  pack_hc_kernel<<<(int)(HSZ / 256), 256, 0, stream>>>(h0, c0, hbuf, cbuf, (int)HSZ);

  for (int s = 0; s < 64; ++s) {
    lstm_step_kernel<<<dim3(32, 16, 4), 256, 0, stream>>>(
        feat, featT, wcat, biasc,
        hbuf + (size_t)(s & 1) * HSZ, hbuf + (size_t)((s + 1) & 1) * HSZ, cbuf, s);
  }
  head_kernel<<<kB, 256, 0, stream>>>(hbuf, W3, b3, out);
}

// Round 2
// 4358.798 us; speedup vs baseline: 1.3303x; 1.3303x over previous
//
#include <hip/hip_runtime.h>
#include <cstddef>
#include <cstdint>

namespace {

constexpr int kB  = 4096;   // batch
constexpr int kIN = 4096;
constexpr int kFS = 4096;
constexpr int kS  = 64;
constexpr int kH  = 512;
constexpr int kNG = 2048;   // 4*H
constexpr int kKC = 576;    // 64 (input slice) + 512 (hidden)
constexpr int kKTiles = kKC / 32;  // 18

typedef __bf16 bf16_t;
typedef __bf16 bfrag  __attribute__((ext_vector_type(8)));
typedef __bf16 bf16v4 __attribute__((ext_vector_type(4)));
typedef float  f32x4  __attribute__((ext_vector_type(4)));

__device__ __forceinline__ void gload16(const void* g, void* l) {
  __builtin_amdgcn_global_load_lds(
      (const __attribute__((address_space(1))) void*)g,
      (__attribute__((address_space(3))) void*)l, 16, 0, 0);
}

__device__ __forceinline__ float sigf(float x) { return 1.0f / (1.0f + __expf(-x)); }
// fast tanh: 1 - 2/(e^{2x}+1); saturates correctly for |x| large (inf -> 1, 0 -> -1)
__device__ __forceinline__ float tanh_fast(float x) {
  float e = __expf(2.0f * x);
  return 1.0f - 2.0f / (e + 1.0f);
}

// ---------------- pack kernels ----------------

__global__ __launch_bounds__(256) void f2b4_kernel(const float* __restrict__ in,
                                                   bf16_t* __restrict__ out, int n4) {
  int i = blockIdx.x * 256 + threadIdx.x;
  if (i >= n4) return;
  float4 v = reinterpret_cast<const float4*>(in)[i];
  bf16v4 o = {(bf16_t)v.x, (bf16_t)v.y, (bf16_t)v.z, (bf16_t)v.w};
  *reinterpret_cast<bf16v4*>(out + (size_t)i * 4) = o;
}

// Wcat[m] (2048 x 576) bf16, rows gate-interleaved: new row u*4+gate <- old row gate*512+u.
// k<64: Wih, k>=64: Whh. m: 0=left, 1=right, 2=up/down (shared).
__global__ __launch_bounds__(256) void pack_wcat_kernel(
    const float* __restrict__ Wih_l, const float* __restrict__ Whh_l,
    const float* __restrict__ Wih_r, const float* __restrict__ Whh_r,
    const float* __restrict__ Wih_d, const float* __restrict__ Whh_d,
    bf16_t* __restrict__ wcat) {
  int idx = blockIdx.x * 256 + threadIdx.x;
  if (idx >= 3 * kNG * kKC) return;
  int m = idx / (kNG * kKC);
  int rem = idx - m * (kNG * kKC);
  int rr = rem / kKC;
  int k  = rem - rr * kKC;
  int u = rr >> 2, g = rr & 3;
  int orow = g * kH + u;
  const float* Wih = (m == 0) ? Wih_l : (m == 1) ? Wih_r : Wih_d;
  const float* Whh = (m == 0) ? Whh_l : (m == 1) ? Whh_r : Whh_d;
  float v = (k < 64) ? Wih[(size_t)orow * 64 + k] : Whh[(size_t)orow * 512 + (k - 64)];
  wcat[idx] = (bf16_t)v;
}

__global__ __launch_bounds__(256) void pack_bias_kernel(
    const float* __restrict__ bih_l, const float* __restrict__ bhh_l,
    const float* __restrict__ bih_r, const float* __restrict__ bhh_r,
    const float* __restrict__ bih_d, const float* __restrict__ bhh_d,
    float* __restrict__ biasc) {
  int idx = blockIdx.x * 256 + threadIdx.x;
  if (idx >= 3 * kNG) return;
  int m = idx / kNG;
  int rr = idx - m * kNG;
  int u = rr >> 2, g = rr & 3;
  int orow = g * kH + u;
  const float* bi = (m == 0) ? bih_l : (m == 1) ? bih_r : bih_d;
  const float* bh = (m == 0) ? bhh_l : (m == 1) ? bhh_r : bhh_d;
  biasc[idx] = bi[orow] + bh[orow];
}

__global__ __launch_bounds__(256) void pack_hc_kernel(const float* __restrict__ h0,
                                                      const float* __restrict__ c0,
                                                      bf16_t* __restrict__ hbuf0,
                                                      float* __restrict__ cbuf, int n) {
  int i = blockIdx.x * 256 + threadIdx.x;
  if (i >= n) return;
  hbuf0[i] = (bf16_t)h0[i];
  cbuf[i]  = c0[i];
}

// per-batch-row 64x64 transpose: featT[b][t*64+s] = feat[b][s*64+t]
__global__ __launch_bounds__(256) void transpose64_kernel(const bf16_t* __restrict__ feat,
                                                          bf16_t* __restrict__ featT) {
  __shared__ bf16_t tile[64][65];
  const int b = blockIdx.x;
  const bf16_t* src = feat + (size_t)b * kFS;
  bf16_t* dst = featT + (size_t)b * kFS;
  for (int i = threadIdx.x; i < 4096; i += 256) tile[i >> 6][i & 63] = src[i];
  __syncthreads();
  for (int i = threadIdx.x; i < 4096; i += 256) dst[i] = tile[i & 63][i >> 6];
}

// ---------------- feat GEMM: feat = relu(x @ W1^T + b1), bf16 in/out, fp32 acc ----------------

__global__ __launch_bounds__(256, 4) void gemm_feat_kernel(
    const bf16_t* __restrict__ X, const bf16_t* __restrict__ W,
    const float* __restrict__ b1, bf16_t* __restrict__ feat) {
  __shared__ bf16_t As[128 * 32];
  __shared__ bf16_t Bs[128 * 32];
  const int t = threadIdx.x;
  // XCD-aware swizzle: grid 1024 (%8==0), bm fastest -> each XCD caches 4 B-panels
  const int bid = blockIdx.x;
  const int widx = (bid & 7) * 128 + (bid >> 3);
  const int bm = widx & 31, bn = widx >> 5;
  const int w = t >> 6, l = t & 63;
  const int wm = (w >> 1) * 64, wn = (w & 1) * 64;
  const int sr = t >> 2, sk = (t & 3) * 8;
  const int lr = l & 15, lk = (l >> 4) * 8;
  const int lrow4 = (l >> 4) * 4;

  f32x4 acc[4][4];
#pragma unroll
  for (int i = 0; i < 4; ++i)
#pragma unroll
    for (int j = 0; j < 4; ++j) acc[i][j] = (f32x4){0.f, 0.f, 0.f, 0.f};

  const bf16_t* ga = X + (size_t)(bm * 128 + sr) * kIN + sk;
  const bf16_t* gb = W + (size_t)(bn * 128 + sr) * kIN + sk;
  bf16_t* lA = As + w * 512;
  bf16_t* lB = Bs + w * 512;

  for (int kt = 0; kt < kIN / 32; ++kt) {
    gload16(ga, lA);
    gload16(ga + (size_t)64 * kIN, lA + 2048);
    gload16(gb, lB);
    gload16(gb + (size_t)64 * kIN, lB + 2048);
    ga += 32; gb += 32;
    __syncthreads();
    bfrag a[4], b[4];
#pragma unroll
    for (int mi = 0; mi < 4; ++mi)
      a[mi] = *reinterpret_cast<const bfrag*>(&As[(wm + mi * 16 + lr) * 32 + lk]);
#pragma unroll
    for (int ni = 0; ni < 4; ++ni)
      b[ni] = *reinterpret_cast<const bfrag*>(&Bs[(wn + ni * 16 + lr) * 32 + lk]);
#pragma unroll
    for (int mi = 0; mi < 4; ++mi)
#pragma unroll
      for (int ni = 0; ni < 4; ++ni)
        acc[mi][ni] = __builtin_amdgcn_mfma_f32_16x16x32_bf16(a[mi], b[ni], acc[mi][ni], 0, 0, 0);
    __syncthreads();
  }

#pragma unroll
  for (int ni = 0; ni < 4; ++ni) {
    const int col = bn * 128 + wn + ni * 16 + lr;
    const float bb = b1[col];
#pragma unroll
    for (int mi = 0; mi < 4; ++mi) {
#pragma unroll
      for (int r = 0; r < 4; ++r) {
        const int row = bm * 128 + wm + mi * 16 + lrow4 + r;
        float v = acc[mi][ni][r] + bb;
        feat[(size_t)row * kFS + col] = (bf16_t)fmaxf(v, 0.0f);
      }
    }
  }
}

// ---------------- fused LSTM step: g = [x_s | h] @ Wcat^T + b -> gates -> c,h ----------------
// LDS plan: 16.9 KB total. As/Bs (16 KB) staging during K-loop; after the loop the same
// memory is reused as a 32x132 fp32 quarter-tile Gs for the gate repack (4 passes).

__global__ __launch_bounds__(256, 4) void lstm_step_kernel(
    const bf16_t* __restrict__ feat, const bf16_t* __restrict__ featT,
    const bf16_t* __restrict__ wcat, const float* __restrict__ biasc,
    const bf16_t* __restrict__ hin, bf16_t* __restrict__ hout,
    float* __restrict__ cbuf, int s) {
  __shared__ __align__(16) unsigned char smem[32 * 132 * 4];  // 16896 B >= 16384 B
  bf16_t* As = (bf16_t*)smem;            // 128 rows x 32
  bf16_t* Bs = (bf16_t*)(smem + 8192);   // 128 rows x 32
  float*  Gs = (float*)smem;             // 32 rows x 132 (post K-loop)

  const int t = threadIdx.x;
  // XCD-aware swizzle: grid 2048 (%8==0). bn fastest within cell -> per-XCD chunk is
  // one cell's full B-panel (2.36 MB) + 16 A-tiles (2.36 MB); same XCD keeps the same
  // cell's weights warm in its L2 across all 64 step launches.
  const int bid = blockIdx.x;
  const int widx = (bid & 7) * 256 + (bid >> 3);
  const int cell = widx >> 9;
  const int rwk  = widx & 511;
  const int bm = rwk >> 4, bn = rwk & 15;
  const int w = t >> 6, l = t & 63;
  const int wm = (w >> 1) * 64, wn = (w & 1) * 64;
  const int sr = t >> 2, sk = (t & 3) * 8;
  const int lr = l & 15, lk = (l >> 4) * 8;
  const int lrow4 = (l >> 4) * 4;

  const bf16_t* xsrc = (cell < 2) ? feat : featT;
  const int off = ((cell & 1) ? (63 - s) : s) * 64;
  const int mat = (cell < 2) ? cell : 2;
  const bf16_t* Wm = wcat + (size_t)mat * kNG * kKC;
  const bf16_t* hc = hin + (size_t)cell * kB * kH;

  f32x4 acc[4][4];
#pragma unroll
  for (int i = 0; i < 4; ++i)
#pragma unroll
    for (int j = 0; j < 4; ++j) acc[i][j] = (f32x4){0.f, 0.f, 0.f, 0.f};

  const bf16_t* gax = xsrc + (size_t)(bm * 128 + sr) * kFS + off + sk;
  const bf16_t* gah = hc + (size_t)(bm * 128 + sr) * kH + sk;
  const bf16_t* gb  = Wm + (size_t)(bn * 128 + sr) * kKC + sk;
  bf16_t* lA = As + w * 512;
  bf16_t* lB = Bs + w * 512;

  for (int kt = 0; kt < kKTiles; ++kt) {
    if (kt < 2) {  // input-slice part of K (contiguous 64 cols of feat/featT)
      const bf16_t* ga = gax + kt * 32;
      gload16(ga, lA);
      gload16(ga + (size_t)64 * kFS, lA + 2048);
    } else {       // hidden part of K
      const bf16_t* ga = gah + (kt - 2) * 32;
      gload16(ga, lA);
      gload16(ga + (size_t)64 * kH, lA + 2048);
    }
    gload16(gb, lB);
    gload16(gb + (size_t)64 * kKC, lB + 2048);
    gb += 32;
    __syncthreads();
    bfrag a[4], b[4];
#pragma unroll
    for (int mi = 0; mi < 4; ++mi)
      a[mi] = *reinterpret_cast<const bfrag*>(&As[(wm + mi * 16 + lr) * 32 + lk]);
#pragma unroll
    for (int ni = 0; ni < 4; ++ni)
      b[ni] = *reinterpret_cast<const bfrag*>(&Bs[(wn + ni * 16 + lr) * 32 + lk]);
#pragma unroll
    for (int mi = 0; mi < 4; ++mi)
#pragma unroll
      for (int ni = 0; ni < 4; ++ni)
        acc[mi][ni] = __builtin_amdgcn_mfma_f32_16x16x32_bf16(a[mi], b[ni], acc[mi][ni], 0, 0, 0);
    __syncthreads();
  }

  // Epilogue: 4 quarter passes. Pass p: half = p>>1 (which waves' acc), rows
  // [half*64 + (p&1)*32, +32) of the 128-row tile land in Gs, then all threads
  // apply gates and update c/h. Gs aliases the dead As/Bs memory.
  const float* biasn = biasc + mat * kNG + bn * 128;
#pragma unroll
  for (int pass = 0; pass < 4; ++pass) {
    const int half = pass >> 1;
    const int mlo  = (pass & 1) * 2;
    if ((w >> 1) == half) {
#pragma unroll
      for (int ni = 0; ni < 4; ++ni) {
        const int colL = wn + ni * 16 + lr;
        const float bb = biasn[colL];
#pragma unroll
        for (int mi = mlo; mi < mlo + 2; ++mi)
#pragma unroll
          for (int r = 0; r < 4; ++r)
            Gs[((mi - mlo) * 16 + lrow4 + r) * 132 + colL] = acc[mi][ni][r] + bb;
      }
    }
    __syncthreads();
#pragma unroll
    for (int it = 0; it < 4; ++it) {
      const int ci = it * 256 + t;          // 32 rows x 32 units
      const int rowL = ci >> 5;
      const int u = ci & 31;
      const float4 g4 = *reinterpret_cast<const float4*>(&Gs[rowL * 132 + u * 4]);
      const float iv = sigf(g4.x);
      const float fv = sigf(g4.y);
      const float gv = tanh_fast(g4.z);
      const float ov = sigf(g4.w);
      const int batch = bm * 128 + half * 64 + mlo * 16 + rowL;
      const int unit = bn * 32 + u;
      const size_t cidx = ((size_t)cell * kB + batch) * kH + unit;
      const float cn = fv * cbuf[cidx] + iv * gv;
      cbuf[cidx] = cn;
      hout[cidx] = (bf16_t)(ov * tanh_fast(cn));
    }
    __syncthreads();
  }
}

// ---------------- head: logits = [hl|hr|hu|hd] @ W3^T + b3 ; log_softmax ----------------

__global__ __launch_bounds__(256) void head_kernel(const bf16_t* __restrict__ hfin,
                                                   const float* __restrict__ W3,
                                                   const float* __restrict__ b3,
                                                   float* __restrict__ out) {
  const int b = blockIdx.x, t = threadIdx.x;
  float acc[10];
#pragma unroll
  for (int j = 0; j < 10; ++j) acc[j] = 0.f;
  for (int k = t; k < 2048; k += 256) {
    const int cell = k >> 9, u = k & 511;
    const float hv = (float)hfin[((size_t)cell * kB + b) * kH + u];
#pragma unroll
    for (int j = 0; j < 10; ++j) acc[j] += hv * W3[j * 2048 + k];
  }
  __shared__ float red[256];
  __shared__ float logits[10];
  for (int j = 0; j < 10; ++j) {
    red[t] = acc[j];
    __syncthreads();
    for (int o2 = 128; o2 > 0; o2 >>= 1) {
      if (t < o2) red[t] += red[t + o2];
      __syncthreads();
    }
    if (t == 0) logits[j] = red[0] + b3[j];
    __syncthreads();
  }
  if (t == 0) {
    float mx = logits[0];
    for (int j = 1; j < 10; ++j) mx = fmaxf(mx, logits[j]);
    float se = 0.f;
    for (int j = 0; j < 10; ++j) se += expf(logits[j] - mx);
    const float lse = mx + logf(se);
    for (int j = 0; j < 10; ++j) out[(size_t)b * 10 + j] = logits[j] - lse;
  }
}

}  // namespace

extern "C" void kernel_launch(void* const* d_in, const int* in_sizes, int n_in,
                              void* d_out, int out_size, void* d_ws, size_t ws_size,
                              hipStream_t stream) {
  const float* x     = (const float*)d_in[0];
  const float* h0    = (const float*)d_in[1];
  const float* c0    = (const float*)d_in[2];
  const float* W1    = (const float*)d_in[3];
  const float* b1    = (const float*)d_in[4];
  const float* Wih_l = (const float*)d_in[5];
  const float* Whh_l = (const float*)d_in[6];
  const float* bih_l = (const float*)d_in[7];
  const float* bhh_l = (const float*)d_in[8];
  const float* Wih_r = (const float*)d_in[9];
  const float* Whh_r = (const float*)d_in[10];
  const float* bih_r = (const float*)d_in[11];
  const float* bhh_r = (const float*)d_in[12];
  const float* Wih_d = (const float*)d_in[13];
  const float* Whh_d = (const float*)d_in[14];
  const float* bih_d = (const float*)d_in[15];
  const float* bhh_d = (const float*)d_in[16];
  const float* W3    = (const float*)d_in[17];
  const float* b3    = (const float*)d_in[18];
  float* out = (float*)d_out;

  char* p = (char*)d_ws;
  auto take = [&](size_t bytes) {
    char* r = p;
    p += (bytes + 255) & ~(size_t)255;
    return r;
  };
  bf16_t* xb    = (bf16_t*)take((size_t)kB * kIN * 2);   // later reused as featT
  bf16_t* w1b   = (bf16_t*)take((size_t)kFS * kIN * 2);  // later reused as hbuf (2 slots)
  bf16_t* feat  = (bf16_t*)take((size_t)kB * kFS * 2);
  bf16_t* wcat  = (bf16_t*)take((size_t)3 * kNG * kKC * 2);
  float*  biasc = (float*)take((size_t)3 * kNG * 4);
  float*  cbuf  = (float*)take((size_t)4 * kB * kH * 4);
  bf16_t* featT = xb;   // safe: gemm_feat (reads xb) precedes transpose (writes featT)
  bf16_t* hbuf  = w1b;  // safe: gemm_feat (reads w1b) precedes pack_hc; 2*4*B*H*2 == FS*IN*2
  const size_t HSZ = (size_t)4 * kB * kH;

  f2b4_kernel<<<(kB * kIN / 4) / 256, 256, 0, stream>>>(x, xb, kB * kIN / 4);
  f2b4_kernel<<<(kFS * kIN / 4) / 256, 256, 0, stream>>>(W1, w1b, kFS * kIN / 4);
  gemm_feat_kernel<<<dim3(1024), 256, 0, stream>>>(xb, w1b, b1, feat);
  transpose64_kernel<<<kB, 256, 0, stream>>>(feat, featT);
  pack_wcat_kernel<<<(3 * kNG * kKC + 255) / 256, 256, 0, stream>>>(
      Wih_l, Whh_l, Wih_r, Whh_r, Wih_d, Whh_d, wcat);
  pack_bias_kernel<<<(3 * kNG + 255) / 256, 256, 0, stream>>>(
      bih_l, bhh_l, bih_r, bhh_r, bih_d, bhh_d, biasc);
  pack_hc_kernel<<<(int)(HSZ / 256), 256, 0, stream>>>(h0, c0, hbuf, cbuf, (int)HSZ);

  for (int s = 0; s < 64; ++s) {
    lstm_step_kernel<<<dim3(2048), 256, 0, stream>>>(
        feat, featT, wcat, biasc,
        hbuf + (size_t)(s & 1) * HSZ, hbuf + (size_t)((s + 1) & 1) * HSZ, cbuf, s);
  }
  head_kernel<<<kB, 256, 0, stream>>>(hbuf, W3, b3, out);
}